// Round 8
// baseline (97.706 us; speedup 1.0000x reference)
//
#include <hip/hip_runtime.h>
#include <math.h>

#define HW    64
#define NPIX  32768

typedef __attribute__((ext_vector_type(8))) short bf16x8;
typedef __attribute__((ext_vector_type(8))) short short8v;
typedef __attribute__((ext_vector_type(4))) float f32x4;

static __device__ inline short f2bf(float f) {
    union { float f; unsigned u; } v; v.f = f;
    unsigned r = v.u + 0x7fff + ((v.u >> 16) & 1);   // RNE
    return (short)(r >> 16);
}
static __device__ inline float bf2f(short s) {
    union { unsigned u; float f; } v; v.u = ((unsigned)(unsigned short)s) << 16;
    return v.f;
}

// ---------------------------------------------------------------------------
// Prep: wt2[f][o][c] bf16 (main weight), wc2[f][ch32][c] bf16 (off+mod, pad 32)
// ---------------------------------------------------------------------------
__global__ void k_prep(const float* __restrict__ w,
                       const float* __restrict__ w_off,
                       const float* __restrict__ w_mod,
                       short* __restrict__ wt2, short* __restrict__ wc2) {
    int t = blockIdx.x * 256 + threadIdx.x;
    if (t < 9 * 64 * 64) {
        int c = t & 63, o = (t >> 6) & 63, f = t >> 12;
        wt2[t] = f2bf(w[(o * 64 + c) * 9 + f]);
    }
    int u = t - 9 * 64 * 64;
    if (u >= 0 && u < 9 * 32 * 64) {
        int c = u & 63, ch = (u >> 6) & 31, f = u >> 11;
        float v = 0.f;
        if (ch < 18)      v = w_off[(ch * 64 + c) * 9 + f];
        else if (ch < 27) v = w_mod[((ch - 18) * 64 + c) * 9 + f];
        wc2[u] = f2bf(v);
    }
}

// ---------------------------------------------------------------------------
// Transpose x NCHW fp32 -> NHWC bf16 (xt[b][y][x][c]); block 256, grid B*H.
// ---------------------------------------------------------------------------
__global__ __launch_bounds__(256) void k_transpose(const float* __restrict__ x,
                                                   short* __restrict__ xt) {
    __shared__ float s[64 * 65];
    int tid = threadIdx.x;
    int by  = blockIdx.x;
    int b = by >> 6, y = by & 63;
    const float* xb = x + ((size_t)b * 64) * 4096 + y * 64;
    #pragma unroll
    for (int q = 0; q < 4; ++q) {
        int fi = q * 256 + tid;
        int c = fi >> 4, xq = (fi & 15) * 4;
        float4 v = *(const float4*)(xb + (size_t)c * 4096 + xq);
        s[c * 65 + xq + 0] = v.x; s[c * 65 + xq + 1] = v.y;
        s[c * 65 + xq + 2] = v.z; s[c * 65 + xq + 3] = v.w;
    }
    __syncthreads();
    short* dst = xt + ((size_t)(b * 64 + y)) * 4096;
    #pragma unroll
    for (int q = 0; q < 4; ++q) {
        int fi = q * 256 + tid;
        int xx = fi >> 4, c = (fi & 15) * 4;
        short4 v = make_short4(f2bf(s[(c + 0) * 65 + xx]), f2bf(s[(c + 1) * 65 + xx]),
                               f2bf(s[(c + 2) * 65 + xx]), f2bf(s[(c + 3) * 65 + xx]));
        *(short4*)(dst + xx * 64 + c) = v;
    }
}

// ---------------------------------------------------------------------------
// conv+meta kernel: per full row (b,i), 256 thr / 4 waves.
//  ph1: stage 3 rows x 68 cells bf16 (swizzled)   ph2: offset/mask conv MFMA
//  ph3: bilinear meta -> global metaW / metaO (corner = byte offset into xt[b])
// LDS = 26112 (window) + 8448 (s_out) = 34560 B -> 4 blocks/CU.
// ---------------------------------------------------------------------------
__global__ __launch_bounds__(256) void k_convmeta(
        const short* __restrict__ xt, const short* __restrict__ wc2,
        const float* __restrict__ b_off, const float* __restrict__ b_mod,
        float4* __restrict__ metaW, int4* __restrict__ metaO) {
    __shared__ __align__(16) char smem[34816];
    float* s_out = (float*)(smem + 26112);           // [32ch][66]

    int tid  = threadIdx.x;
    int lane = tid & 63;
    int wv   = __builtin_amdgcn_readfirstlane((int)(tid >> 6));
    int blk  = blockIdx.x;                           // b*64 + i
    int b = blk >> 6, i = blk & 63;
    const short* xs = xt + (size_t)b * 262144;

    int arow = lane & 15, cg = lane >> 4, cgb = cg * 8;

    // ---- ph1: stage rows i-1..i+1, cols -2..65 (68 cells x 128 B, swizzled)
    for (int u = tid; u < 1632; u += 256) {          // 204 cells x 8 chunks
        int cell = u >> 3, chunk = u & 7;
        int r = cell / 68, cc = cell - r * 68;
        int y = i - 1 + r, gx = cc - 2;
        short8v v = (short8v){0,0,0,0,0,0,0,0};
        if (((unsigned)y < 64u) & ((unsigned)gx < 64u))
            v = *(const short8v*)(xs + ((y << 6) + gx) * 64 + chunk * 8);
        *(short8v*)(smem + cell * 128 + ((chunk * 16) ^ ((cell & 7) << 4))) = v;
    }
    __syncthreads();

    // ---- ph2: conv. wave wv: nf = wv&1 (ch half), mg = wv>>1 (px half).
    {
        int nf = wv & 1, mg = wv >> 1;
        f32x4 accc[2];
        accc[0] = (f32x4){0.f,0.f,0.f,0.f};
        accc[1] = (f32x4){0.f,0.f,0.f,0.f};
        #pragma unroll
        for (int ky = 0; ky < 3; ++ky)
            #pragma unroll
            for (int kx = 0; kx < 3; ++kx) {
                int f = ky * 3 + kx;
                #pragma unroll
                for (int kk = 0; kk < 2; ++kk) {
                    bf16x8 bq = *(const bf16x8*)(wc2 + (f * 32 + nf * 16 + arow) * 64
                                                 + kk * 32 + cgb);
                    #pragma unroll
                    for (int mm = 0; mm < 2; ++mm) {
                        int cell = ky * 68 + mg * 32 + mm * 16 + arow + kx + 1;
                        const char* ap = smem + cell * 128
                                       + ((kk * 64 + cg * 16) ^ ((cell & 7) << 4));
                        accc[mm] = __builtin_amdgcn_mfma_f32_16x16x32_bf16(
                            *(const bf16x8*)ap, bq, accc[mm], 0, 0, 0);
                    }
                }
            }
        #pragma unroll
        for (int mm = 0; mm < 2; ++mm)
            #pragma unroll
            for (int r = 0; r < 4; ++r)
                s_out[(nf * 16 + arow) * 66 + mg * 32 + mm * 16 + cg * 4 + r] = accc[mm][r];
    }
    __syncthreads();

    // ---- ph3: meta (9 taps x 64 px), strided
    int pixBase = blk * 64;
    for (int u = tid; u < 576; u += 256) {
        int f = u >> 6, p = u & 63;
        float dy = s_out[(2 * f)     * 66 + p] + b_off[2 * f];
        float dx = s_out[(2 * f + 1) * 66 + p] + b_off[2 * f + 1];
        float mv = s_out[(18 + f)    * 66 + p] + b_mod[f];
        float m  = 1.f / (1.f + expf(-mv));

        float ys  = (float)(i - 1 + f / 3) + dy;
        float xs2 = (float)(p - 1 + f % 3) + dx;
        float y0f = floorf(ys), x0f = floorf(xs2);
        int   y0  = (int)y0f,   x0  = (int)x0f;
        float fy = ys - y0f, fx = xs2 - x0f;

        bool vy0 = (unsigned)y0       < 64u, vy1 = (unsigned)(y0 + 1) < 64u;
        bool vx0 = (unsigned)x0       < 64u, vx1 = (unsigned)(x0 + 1) < 64u;
        float w00 = (vy0 & vx0) ? (1.f - fy) * (1.f - fx) * m : 0.f;
        float w01 = (vy0 & vx1) ? (1.f - fy) * fx         * m : 0.f;
        float w10 = (vy1 & vx0) ? fy         * (1.f - fx) * m : 0.f;
        float w11 = (vy1 & vx1) ? fy         * fx         * m : 0.f;

        int y0c = min(max(y0, 0), 63), y1c = min(max(y0 + 1, 0), 63);
        int x0c = min(max(x0, 0), 63), x1c = min(max(x0 + 1, 0), 63);

        metaW[f * NPIX + pixBase + p] = make_float4(w00, w01, w10, w11);
        metaO[f * NPIX + pixBase + p] = make_int4(((y0c << 6) + x0c) * 128,
                                                  ((y0c << 6) + x1c) * 128,
                                                  ((y1c << 6) + x0c) * 128,
                                                  ((y1c << 6) + x1c) * 128);
    }
}

// ---------------------------------------------------------------------------
// k_zero: out <- bias broadcast (atomic accumulation base). Grid 2048 x 256.
// ---------------------------------------------------------------------------
__global__ __launch_bounds__(256) void k_zero(const float* __restrict__ bias,
                                              float* __restrict__ out) {
    int t = blockIdx.x * 256 + threadIdx.x;          // float4 index
    int base = t * 4;
    float bv = bias[(base >> 12) & 63];
    *(float4*)(out + base) = make_float4(bv, bv, bv, bv);
}

// ---------------------------------------------------------------------------
// k_gather: tap-parallel deformable gather + MFMA + atomic accumulate.
// Grid (2048 px-groups, 9 taps), 64 threads = 1 wave, NO LDS, NO barriers.
// Wave: 16 px x 64 Cout x 64 K for ONE tap.
//   lane: arow = px (n-col), cg = k-chunk. B-frag gathered in registers;
//   A-frags (weights) stream from L2-hot wt2. acc -> 16 atomicAdd f32.
// ---------------------------------------------------------------------------
__global__ __launch_bounds__(64) void k_gather(
        const short* __restrict__ xt,
        const float4* __restrict__ metaW, const int4* __restrict__ metaO,
        const short* __restrict__ wt2, float* __restrict__ out) {
    int lane = threadIdx.x;
    int f    = blockIdx.y;
    int pixBase = blockIdx.x * 16;
    int arow = lane & 15, cg = lane >> 4, cgb = cg * 8;
    int P = pixBase + arow;
    int b = P >> 12;
    const char* xbb = (const char*)(xt + (size_t)b * 262144);

    float4 mW = metaW[f * NPIX + P];
    int4   mO = metaO[f * NPIX + P];

    f32x4 acc[4];
    #pragma unroll
    for (int mf = 0; mf < 4; ++mf) acc[mf] = (f32x4){0.f,0.f,0.f,0.f};

    #pragma unroll
    for (int kk = 0; kk < 2; ++kk) {
        int off = kk * 64 + cg * 16;                 // byte offset within corner row
        bf16x8 c0 = *(const bf16x8*)(xbb + mO.x + off);
        bf16x8 c1 = *(const bf16x8*)(xbb + mO.y + off);
        bf16x8 c2 = *(const bf16x8*)(xbb + mO.z + off);
        bf16x8 c3 = *(const bf16x8*)(xbb + mO.w + off);
        bf16x8 sf;
        #pragma unroll
        for (int j = 0; j < 8; ++j) {
            float s = mW.x * bf2f(c0[j]) + mW.y * bf2f(c1[j])
                    + mW.z * bf2f(c2[j]) + mW.w * bf2f(c3[j]);
            sf[j] = f2bf(s);
        }
        #pragma unroll
        for (int mf = 0; mf < 4; ++mf) {
            const short* wp = wt2 + (f * 64 + mf * 16 + arow) * 64 + kk * 32 + cgb;
            acc[mf] = __builtin_amdgcn_mfma_f32_16x16x32_bf16(
                *(const bf16x8*)wp, sf, acc[mf], 0, 0, 0);
        }
    }

    // acc element r of frag mf: o = mf*16 + cg*4 + r, pixel = P
    int ii = (P >> 6) & 63, jj = P & 63;
    float* ob = out + (size_t)b * 262144 + ii * 64 + jj;
    #pragma unroll
    for (int mf = 0; mf < 4; ++mf)
        #pragma unroll
        for (int r = 0; r < 4; ++r) {
            int o = mf * 16 + cg * 4 + r;
            atomicAdd(ob + (size_t)o * 4096, acc[mf][r]);
        }
}

// ---------------------------------------------------------------------------
extern "C" void kernel_launch(void* const* d_in, const int* in_sizes, int n_in,
                              void* d_out, int out_size, void* d_ws, size_t ws_size,
                              hipStream_t stream) {
    const float* x     = (const float*)d_in[0];
    const float* w_off = (const float*)d_in[1];
    const float* b_off = (const float*)d_in[2];
    const float* w_mod = (const float*)d_in[3];
    const float* b_mod = (const float*)d_in[4];
    const float* w     = (const float*)d_in[5];
    const float* bias  = (const float*)d_in[6];
    float* out = (float*)d_out;

    char* ws = (char*)d_ws;
    short*  xt    = (short*)(ws);                    //  4,194,304 B
    short*  wt2   = (short*)(ws + 4194304);          //     73,728 B
    short*  wc2   = (short*)(ws + 4268032);          //     36,864 B
    float4* metaW = (float4*)(ws + 4304896);         //  4,718,592 B
    int4*   metaO = (int4*)(ws + 9023488);           //  4,718,592 B

    hipLaunchKernelGGL(k_prep,      dim3(216),       dim3(256), 0, stream, w, w_off, w_mod, wt2, wc2);
    hipLaunchKernelGGL(k_transpose, dim3(512),       dim3(256), 0, stream, x, xt);
    hipLaunchKernelGGL(k_convmeta,  dim3(512),       dim3(256), 0, stream,
                       xt, wc2, b_off, b_mod, metaW, metaO);
    hipLaunchKernelGGL(k_zero,      dim3(2048),      dim3(256), 0, stream, bias, out);
    hipLaunchKernelGGL(k_gather,    dim3(2048, 9),   dim3(64),  0, stream,
                       xt, metaW, metaO, wt2, out);
}

// Round 9
// 69.224 us; speedup vs baseline: 1.4115x; 1.4115x over previous
//
#include <hip/hip_runtime.h>
#include <math.h>

#define HW    64
#define NPIX  32768

typedef __attribute__((ext_vector_type(8))) short bf16x8;
typedef __attribute__((ext_vector_type(8))) short short8v;
typedef __attribute__((ext_vector_type(4))) float f32x4;

static __device__ inline short f2bf(float f) {
    union { float f; unsigned u; } v; v.f = f;
    unsigned r = v.u + 0x7fff + ((v.u >> 16) & 1);   // RNE
    return (short)(r >> 16);
}
static __device__ inline float bf2f(short s) {
    union { unsigned u; float f; } v; v.u = ((unsigned)(unsigned short)s) << 16;
    return v.f;
}

// ---------------------------------------------------------------------------
// Prep: wt2[f][o][c] bf16 (main weight), wc2[f][ch32][c] bf16 (off+mod, pad 32)
// ---------------------------------------------------------------------------
__global__ void k_prep(const float* __restrict__ w,
                       const float* __restrict__ w_off,
                       const float* __restrict__ w_mod,
                       short* __restrict__ wt2, short* __restrict__ wc2) {
    int t = blockIdx.x * 256 + threadIdx.x;
    if (t < 9 * 64 * 64) {
        int c = t & 63, o = (t >> 6) & 63, f = t >> 12;
        wt2[t] = f2bf(w[(o * 64 + c) * 9 + f]);
    }
    int u = t - 9 * 64 * 64;
    if (u >= 0 && u < 9 * 32 * 64) {
        int c = u & 63, ch = (u >> 6) & 31, f = u >> 11;
        float v = 0.f;
        if (ch < 18)      v = w_off[(ch * 64 + c) * 9 + f];
        else if (ch < 27) v = w_mod[((ch - 18) * 64 + c) * 9 + f];
        wc2[u] = f2bf(v);
    }
}

// ---------------------------------------------------------------------------
// Transpose x NCHW fp32 -> NHWC bf16 (xt[b][y][x][c]); block 256, grid B*H.
// ---------------------------------------------------------------------------
__global__ __launch_bounds__(256) void k_transpose(const float* __restrict__ x,
                                                   short* __restrict__ xt) {
    __shared__ float s[64 * 65];
    int tid = threadIdx.x;
    int by  = blockIdx.x;
    int b = by >> 6, y = by & 63;
    const float* xb = x + ((size_t)b * 64) * 4096 + y * 64;
    #pragma unroll
    for (int q = 0; q < 4; ++q) {
        int fi = q * 256 + tid;
        int c = fi >> 4, xq = (fi & 15) * 4;
        float4 v = *(const float4*)(xb + (size_t)c * 4096 + xq);
        s[c * 65 + xq + 0] = v.x; s[c * 65 + xq + 1] = v.y;
        s[c * 65 + xq + 2] = v.z; s[c * 65 + xq + 3] = v.w;
    }
    __syncthreads();
    short* dst = xt + ((size_t)(b * 64 + y)) * 4096;
    #pragma unroll
    for (int q = 0; q < 4; ++q) {
        int fi = q * 256 + tid;
        int xx = fi >> 4, c = (fi & 15) * 4;
        short4 v = make_short4(f2bf(s[(c + 0) * 65 + xx]), f2bf(s[(c + 1) * 65 + xx]),
                               f2bf(s[(c + 2) * 65 + xx]), f2bf(s[(c + 3) * 65 + xx]));
        *(short4*)(dst + xx * 64 + c) = v;
    }
}

// ---------------------------------------------------------------------------
// conv+meta kernel: per full row (b,i), 256 thr / 4 waves (unchanged from r8).
// ---------------------------------------------------------------------------
__global__ __launch_bounds__(256) void k_convmeta(
        const short* __restrict__ xt, const short* __restrict__ wc2,
        const float* __restrict__ b_off, const float* __restrict__ b_mod,
        float4* __restrict__ metaW, int4* __restrict__ metaO) {
    __shared__ __align__(16) char smem[34816];
    float* s_out = (float*)(smem + 26112);           // [32ch][66]

    int tid  = threadIdx.x;
    int lane = tid & 63;
    int wv   = __builtin_amdgcn_readfirstlane((int)(tid >> 6));
    int blk  = blockIdx.x;                           // b*64 + i
    int b = blk >> 6, i = blk & 63;
    const short* xs = xt + (size_t)b * 262144;

    int arow = lane & 15, cg = lane >> 4, cgb = cg * 8;

    for (int u = tid; u < 1632; u += 256) {          // 204 cells x 8 chunks
        int cell = u >> 3, chunk = u & 7;
        int r = cell / 68, cc = cell - r * 68;
        int y = i - 1 + r, gx = cc - 2;
        short8v v = (short8v){0,0,0,0,0,0,0,0};
        if (((unsigned)y < 64u) & ((unsigned)gx < 64u))
            v = *(const short8v*)(xs + ((y << 6) + gx) * 64 + chunk * 8);
        *(short8v*)(smem + cell * 128 + ((chunk * 16) ^ ((cell & 7) << 4))) = v;
    }
    __syncthreads();

    {
        int nf = wv & 1, mg = wv >> 1;
        f32x4 accc[2];
        accc[0] = (f32x4){0.f,0.f,0.f,0.f};
        accc[1] = (f32x4){0.f,0.f,0.f,0.f};
        #pragma unroll
        for (int ky = 0; ky < 3; ++ky)
            #pragma unroll
            for (int kx = 0; kx < 3; ++kx) {
                int f = ky * 3 + kx;
                #pragma unroll
                for (int kk = 0; kk < 2; ++kk) {
                    bf16x8 bq = *(const bf16x8*)(wc2 + (f * 32 + nf * 16 + arow) * 64
                                                 + kk * 32 + cgb);
                    #pragma unroll
                    for (int mm = 0; mm < 2; ++mm) {
                        int cell = ky * 68 + mg * 32 + mm * 16 + arow + kx + 1;
                        const char* ap = smem + cell * 128
                                       + ((kk * 64 + cg * 16) ^ ((cell & 7) << 4));
                        accc[mm] = __builtin_amdgcn_mfma_f32_16x16x32_bf16(
                            *(const bf16x8*)ap, bq, accc[mm], 0, 0, 0);
                    }
                }
            }
        #pragma unroll
        for (int mm = 0; mm < 2; ++mm)
            #pragma unroll
            for (int r = 0; r < 4; ++r)
                s_out[(nf * 16 + arow) * 66 + mg * 32 + mm * 16 + cg * 4 + r] = accc[mm][r];
    }
    __syncthreads();

    int pixBase = blk * 64;
    for (int u = tid; u < 576; u += 256) {
        int f = u >> 6, p = u & 63;
        float dy = s_out[(2 * f)     * 66 + p] + b_off[2 * f];
        float dx = s_out[(2 * f + 1) * 66 + p] + b_off[2 * f + 1];
        float mv = s_out[(18 + f)    * 66 + p] + b_mod[f];
        float m  = 1.f / (1.f + expf(-mv));

        float ys  = (float)(i - 1 + f / 3) + dy;
        float xs2 = (float)(p - 1 + f % 3) + dx;
        float y0f = floorf(ys), x0f = floorf(xs2);
        int   y0  = (int)y0f,   x0  = (int)x0f;
        float fy = ys - y0f, fx = xs2 - x0f;

        bool vy0 = (unsigned)y0       < 64u, vy1 = (unsigned)(y0 + 1) < 64u;
        bool vx0 = (unsigned)x0       < 64u, vx1 = (unsigned)(x0 + 1) < 64u;
        float w00 = (vy0 & vx0) ? (1.f - fy) * (1.f - fx) * m : 0.f;
        float w01 = (vy0 & vx1) ? (1.f - fy) * fx         * m : 0.f;
        float w10 = (vy1 & vx0) ? fy         * (1.f - fx) * m : 0.f;
        float w11 = (vy1 & vx1) ? fy         * fx         * m : 0.f;

        int y0c = min(max(y0, 0), 63), y1c = min(max(y0 + 1, 0), 63);
        int x0c = min(max(x0, 0), 63), x1c = min(max(x0 + 1, 0), 63);

        metaW[f * NPIX + pixBase + p] = make_float4(w00, w01, w10, w11);
        metaO[f * NPIX + pixBase + p] = make_int4(((y0c << 6) + x0c) * 128,
                                                  ((y0c << 6) + x1c) * 128,
                                                  ((y1c << 6) + x0c) * 128,
                                                  ((y1c << 6) + x1c) * 128);
    }
}

// ---------------------------------------------------------------------------
// k_tap: tap-row-parallel deformable gather + MFMA -> f32 partials (NO atomics).
// Grid (2048 px-groups, 3 ky), 64 thr = 1 wave, no LDS, no barriers.
// Wave: 16 px x 64 Cout x K=64 for 3 taps (ky*3+kx), double-buffered corner
// prefetch (load tap kx+1 before computing tap kx).
// Partial layout: partial[(ky*64+o)*32768 + pix].
// ---------------------------------------------------------------------------
__global__ __launch_bounds__(64, 3) void k_tap(
        const short* __restrict__ xt,
        const float4* __restrict__ metaW, const int4* __restrict__ metaO,
        const short* __restrict__ wt2, float* __restrict__ partial) {
    int lane = threadIdx.x;
    int ky   = blockIdx.y;
    int pixBase = blockIdx.x * 16;
    int arow = lane & 15, cg = lane >> 4, cgb = cg * 8;
    int P = pixBase + arow;
    int b = P >> 12;
    const char* xbb = (const char*)(xt + (size_t)b * 262144);

    float4 mW0 = metaW[(ky * 3 + 0) * NPIX + P];
    float4 mW1 = metaW[(ky * 3 + 1) * NPIX + P];
    float4 mW2 = metaW[(ky * 3 + 2) * NPIX + P];
    int4   mO0 = metaO[(ky * 3 + 0) * NPIX + P];
    int4   mO1 = metaO[(ky * 3 + 1) * NPIX + P];
    int4   mO2 = metaO[(ky * 3 + 2) * NPIX + P];

    #define LOADC(dst, mo) {                                                   \
        _Pragma("unroll")                                                      \
        for (int kk = 0; kk < 2; ++kk) {                                       \
            int off = kk * 64 + cg * 16;                                       \
            dst[kk * 4 + 0] = *(const bf16x8*)(xbb + (mo).x + off);            \
            dst[kk * 4 + 1] = *(const bf16x8*)(xbb + (mo).y + off);            \
            dst[kk * 4 + 2] = *(const bf16x8*)(xbb + (mo).z + off);            \
            dst[kk * 4 + 3] = *(const bf16x8*)(xbb + (mo).w + off);            \
        } }

    #define COMPUTE(src, mw, F) {                                              \
        _Pragma("unroll")                                                      \
        for (int kk = 0; kk < 2; ++kk) {                                       \
            bf16x8 sf;                                                         \
            _Pragma("unroll")                                                  \
            for (int j = 0; j < 8; ++j) {                                      \
                float s = (mw).x * bf2f(src[kk * 4 + 0][j])                    \
                        + (mw).y * bf2f(src[kk * 4 + 1][j])                    \
                        + (mw).z * bf2f(src[kk * 4 + 2][j])                    \
                        + (mw).w * bf2f(src[kk * 4 + 3][j]);                   \
                sf[j] = f2bf(s);                                               \
            }                                                                  \
            _Pragma("unroll")                                                  \
            for (int mf = 0; mf < 4; ++mf) {                                   \
                const short* wp = wt2 + ((F) * 64 + mf * 16 + arow) * 64       \
                                + kk * 32 + cgb;                               \
                acc[mf] = __builtin_amdgcn_mfma_f32_16x16x32_bf16(             \
                    *(const bf16x8*)wp, sf, acc[mf], 0, 0, 0);                 \
            }                                                                  \
        } }

    f32x4 acc[4];
    #pragma unroll
    for (int mf = 0; mf < 4; ++mf) acc[mf] = (f32x4){0.f, 0.f, 0.f, 0.f};

    bf16x8 ca[8], cb[8];
    LOADC(ca, mO0);
    LOADC(cb, mO1);                 // in flight during tap 0 compute
    COMPUTE(ca, mW0, ky * 3 + 0);
    LOADC(ca, mO2);                 // in flight during tap 1 compute
    COMPUTE(cb, mW1, ky * 3 + 1);
    COMPUTE(ca, mW2, ky * 3 + 2);
    #undef LOADC
    #undef COMPUTE

    // store partials: o = mf*16 + cg*4 + r, pixel = P
    float* pb = partial + ((size_t)ky << 21);        // 64*32768 floats per ky
    #pragma unroll
    for (int mf = 0; mf < 4; ++mf)
        #pragma unroll
        for (int r = 0; r < 4; ++r) {
            int o = mf * 16 + cg * 4 + r;
            pb[((size_t)o << 15) + P] = acc[mf][r];
        }
}

// ---------------------------------------------------------------------------
// k_reduce: out = bias + sum of 3 ky-partials. Grid 2048 x 256, float4/thread.
// ---------------------------------------------------------------------------
__global__ __launch_bounds__(256) void k_reduce(const float* __restrict__ partial,
                                                const float* __restrict__ bias,
                                                float* __restrict__ out) {
    int t = blockIdx.x * 256 + threadIdx.x;          // float4 index, 0..524287
    int e = t * 4;
    int b = e >> 18, o = (e >> 12) & 63, ij = e & 4095;
    size_t pidx = ((size_t)o << 15) + ((size_t)b << 12) + ij;
    float4 p0 = *(const float4*)(partial + pidx);
    float4 p1 = *(const float4*)(partial + (1u << 21) + pidx);
    float4 p2 = *(const float4*)(partial + (2u << 21) + pidx);
    float bv = bias[o];
    float4 v;
    v.x = p0.x + p1.x + p2.x + bv;
    v.y = p0.y + p1.y + p2.y + bv;
    v.z = p0.z + p1.z + p2.z + bv;
    v.w = p0.w + p1.w + p2.w + bv;
    *(float4*)(out + e) = v;
}

// ---------------------------------------------------------------------------
extern "C" void kernel_launch(void* const* d_in, const int* in_sizes, int n_in,
                              void* d_out, int out_size, void* d_ws, size_t ws_size,
                              hipStream_t stream) {
    const float* x     = (const float*)d_in[0];
    const float* w_off = (const float*)d_in[1];
    const float* b_off = (const float*)d_in[2];
    const float* w_mod = (const float*)d_in[3];
    const float* b_mod = (const float*)d_in[4];
    const float* w     = (const float*)d_in[5];
    const float* bias  = (const float*)d_in[6];
    float* out = (float*)d_out;

    char* ws = (char*)d_ws;
    short*  xt      = (short*)(ws);                  //  4,194,304 B
    short*  wt2     = (short*)(ws + 4194304);        //     73,728 B
    short*  wc2     = (short*)(ws + 4268032);        //     36,864 B
    float4* metaW   = (float4*)(ws + 4304896);       //  4,718,592 B
    int4*   metaO   = (int4*)(ws + 9023488);         //  4,718,592 B
    float*  partial = (float*)(ws + 13742080);       // 25,165,824 B

    hipLaunchKernelGGL(k_prep,      dim3(216),      dim3(256), 0, stream, w, w_off, w_mod, wt2, wc2);
    hipLaunchKernelGGL(k_transpose, dim3(512),      dim3(256), 0, stream, x, xt);
    hipLaunchKernelGGL(k_convmeta,  dim3(512),      dim3(256), 0, stream,
                       xt, wc2, b_off, b_mod, metaW, metaO);
    hipLaunchKernelGGL(k_tap,       dim3(2048, 3),  dim3(64),  0, stream,
                       xt, metaW, metaO, wt2, partial);
    hipLaunchKernelGGL(k_reduce,    dim3(2048),     dim3(256), 0, stream,
                       partial, bias, out);
}

// Round 10
// 61.532 us; speedup vs baseline: 1.5879x; 1.1250x over previous
//
#include <hip/hip_runtime.h>
#include <math.h>

#define HW    64
#define NPIX  32768

typedef __attribute__((ext_vector_type(8))) short bf16x8;
typedef __attribute__((ext_vector_type(8))) short short8v;
typedef __attribute__((ext_vector_type(4))) float f32x4;

static __device__ inline short f2bf(float f) {
    union { float f; unsigned u; } v; v.f = f;
    unsigned r = v.u + 0x7fff + ((v.u >> 16) & 1);   // RNE
    return (short)(r >> 16);
}
static __device__ inline float bf2f(short s) {
    union { unsigned u; float f; } v; v.u = ((unsigned)(unsigned short)s) << 16;
    return v.f;
}

// ---------------------------------------------------------------------------
// Prep: wt2[f][o][c] bf16 (main weight), wc2[f][ch32][c] bf16 (off+mod, pad 32)
// ---------------------------------------------------------------------------
__global__ void k_prep(const float* __restrict__ w,
                       const float* __restrict__ w_off,
                       const float* __restrict__ w_mod,
                       short* __restrict__ wt2, short* __restrict__ wc2) {
    int t = blockIdx.x * 256 + threadIdx.x;
    if (t < 9 * 64 * 64) {
        int c = t & 63, o = (t >> 6) & 63, f = t >> 12;
        wt2[t] = f2bf(w[(o * 64 + c) * 9 + f]);
    }
    int u = t - 9 * 64 * 64;
    if (u >= 0 && u < 9 * 32 * 64) {
        int c = u & 63, ch = (u >> 6) & 31, f = u >> 11;
        float v = 0.f;
        if (ch < 18)      v = w_off[(ch * 64 + c) * 9 + f];
        else if (ch < 27) v = w_mod[((ch - 18) * 64 + c) * 9 + f];
        wc2[u] = f2bf(v);
    }
}

// ---------------------------------------------------------------------------
// Transpose x NCHW fp32 -> NHWC bf16 (xt[b][y][x][c]); block 256, grid B*H.
// ---------------------------------------------------------------------------
__global__ __launch_bounds__(256) void k_transpose(const float* __restrict__ x,
                                                   short* __restrict__ xt) {
    __shared__ float s[64 * 65];
    int tid = threadIdx.x;
    int by  = blockIdx.x;
    int b = by >> 6, y = by & 63;
    const float* xb = x + ((size_t)b * 64) * 4096 + y * 64;
    #pragma unroll
    for (int q = 0; q < 4; ++q) {
        int fi = q * 256 + tid;
        int c = fi >> 4, xq = (fi & 15) * 4;
        float4 v = *(const float4*)(xb + (size_t)c * 4096 + xq);
        s[c * 65 + xq + 0] = v.x; s[c * 65 + xq + 1] = v.y;
        s[c * 65 + xq + 2] = v.z; s[c * 65 + xq + 3] = v.w;
    }
    __syncthreads();
    short* dst = xt + ((size_t)(b * 64 + y)) * 4096;
    #pragma unroll
    for (int q = 0; q < 4; ++q) {
        int fi = q * 256 + tid;
        int xx = fi >> 4, c = (fi & 15) * 4;
        short4 v = make_short4(f2bf(s[(c + 0) * 65 + xx]), f2bf(s[(c + 1) * 65 + xx]),
                               f2bf(s[(c + 2) * 65 + xx]), f2bf(s[(c + 3) * 65 + xx]));
        *(short4*)(dst + xx * 64 + c) = v;
    }
}

// ---------------------------------------------------------------------------
// conv+meta kernel: per full row (b,i), 256 thr / 4 waves (unchanged, proven).
// metaO = byte offsets of the 4 clamped corner rows within xt[b].
// ---------------------------------------------------------------------------
__global__ __launch_bounds__(256) void k_convmeta(
        const short* __restrict__ xt, const short* __restrict__ wc2,
        const float* __restrict__ b_off, const float* __restrict__ b_mod,
        float4* __restrict__ metaW, int4* __restrict__ metaO) {
    __shared__ __align__(16) char smem[34816];
    float* s_out = (float*)(smem + 26112);           // [32ch][66]

    int tid  = threadIdx.x;
    int lane = tid & 63;
    int wv   = __builtin_amdgcn_readfirstlane((int)(tid >> 6));
    int blk  = blockIdx.x;                           // b*64 + i
    int b = blk >> 6, i = blk & 63;
    const short* xs = xt + (size_t)b * 262144;

    int arow = lane & 15, cg = lane >> 4, cgb = cg * 8;

    for (int u = tid; u < 1632; u += 256) {          // 204 cells x 8 chunks
        int cell = u >> 3, chunk = u & 7;
        int r = cell / 68, cc = cell - r * 68;
        int y = i - 1 + r, gx = cc - 2;
        short8v v = (short8v){0,0,0,0,0,0,0,0};
        if (((unsigned)y < 64u) & ((unsigned)gx < 64u))
            v = *(const short8v*)(xs + ((y << 6) + gx) * 64 + chunk * 8);
        *(short8v*)(smem + cell * 128 + ((chunk * 16) ^ ((cell & 7) << 4))) = v;
    }
    __syncthreads();

    {
        int nf = wv & 1, mg = wv >> 1;
        f32x4 accc[2];
        accc[0] = (f32x4){0.f,0.f,0.f,0.f};
        accc[1] = (f32x4){0.f,0.f,0.f,0.f};
        #pragma unroll
        for (int ky = 0; ky < 3; ++ky)
            #pragma unroll
            for (int kx = 0; kx < 3; ++kx) {
                int f = ky * 3 + kx;
                #pragma unroll
                for (int kk = 0; kk < 2; ++kk) {
                    bf16x8 bq = *(const bf16x8*)(wc2 + (f * 32 + nf * 16 + arow) * 64
                                                 + kk * 32 + cgb);
                    #pragma unroll
                    for (int mm = 0; mm < 2; ++mm) {
                        int cell = ky * 68 + mg * 32 + mm * 16 + arow + kx + 1;
                        const char* ap = smem + cell * 128
                                       + ((kk * 64 + cg * 16) ^ ((cell & 7) << 4));
                        accc[mm] = __builtin_amdgcn_mfma_f32_16x16x32_bf16(
                            *(const bf16x8*)ap, bq, accc[mm], 0, 0, 0);
                    }
                }
            }
        #pragma unroll
        for (int mm = 0; mm < 2; ++mm)
            #pragma unroll
            for (int r = 0; r < 4; ++r)
                s_out[(nf * 16 + arow) * 66 + mg * 32 + mm * 16 + cg * 4 + r] = accc[mm][r];
    }
    __syncthreads();

    int pixBase = blk * 64;
    for (int u = tid; u < 576; u += 256) {
        int f = u >> 6, p = u & 63;
        float dy = s_out[(2 * f)     * 66 + p] + b_off[2 * f];
        float dx = s_out[(2 * f + 1) * 66 + p] + b_off[2 * f + 1];
        float mv = s_out[(18 + f)    * 66 + p] + b_mod[f];
        float m  = 1.f / (1.f + expf(-mv));

        float ys  = (float)(i - 1 + f / 3) + dy;
        float xs2 = (float)(p - 1 + f % 3) + dx;
        float y0f = floorf(ys), x0f = floorf(xs2);
        int   y0  = (int)y0f,   x0  = (int)x0f;
        float fy = ys - y0f, fx = xs2 - x0f;

        bool vy0 = (unsigned)y0       < 64u, vy1 = (unsigned)(y0 + 1) < 64u;
        bool vx0 = (unsigned)x0       < 64u, vx1 = (unsigned)(x0 + 1) < 64u;
        float w00 = (vy0 & vx0) ? (1.f - fy) * (1.f - fx) * m : 0.f;
        float w01 = (vy0 & vx1) ? (1.f - fy) * fx         * m : 0.f;
        float w10 = (vy1 & vx0) ? fy         * (1.f - fx) * m : 0.f;
        float w11 = (vy1 & vx1) ? fy         * fx         * m : 0.f;

        int y0c = min(max(y0, 0), 63), y1c = min(max(y0 + 1, 0), 63);
        int x0c = min(max(x0, 0), 63), x1c = min(max(x0 + 1, 0), 63);

        metaW[f * NPIX + pixBase + p] = make_float4(w00, w01, w10, w11);
        metaO[f * NPIX + pixBase + p] = make_int4(((y0c << 6) + x0c) * 128,
                                                  ((y0c << 6) + x1c) * 128,
                                                  ((y1c << 6) + x0c) * 128,
                                                  ((y1c << 6) + x1c) * 128);
    }
}

// ---------------------------------------------------------------------------
// k_sample: im2col bilinear sampling -> S[f][pix][c] bf16 (37.7 MB).
// Wave-task = one (pix, tap): meta loads wave-uniform (s_load), 4 corner
// loads fully coalesced 128 B (lane = channel), interp, 128 B store.
// Grid 2048 x 256 -> 8192 waves x 36 tasks, zero scattered VMEM.
// ---------------------------------------------------------------------------
__global__ __launch_bounds__(256) void k_sample(
        const short* __restrict__ xt,
        const float4* __restrict__ metaW, const int4* __restrict__ metaO,
        short* __restrict__ S) {
    int lane = threadIdx.x & 63;
    int wv   = __builtin_amdgcn_readfirstlane((int)(threadIdx.x >> 6));
    int wg   = blockIdx.x * 4 + wv;                  // 0..8191
    int t0   = wg * 36;
    #pragma unroll 6
    for (int it = 0; it < 36; ++it) {
        int t = t0 + it;                             // uniform: f*NPIX + P
        float4 mW = metaW[t];                        // s_load_dwordx4
        int4   mO = metaO[t];                        // s_load_dwordx4
        int P = t & 32767;
        const char* xbb = (const char*)(xt + ((size_t)(P >> 12)) * 262144);
        short c0 = *(const short*)(xbb + mO.x + lane * 2);
        short c1 = *(const short*)(xbb + mO.y + lane * 2);
        short c2 = *(const short*)(xbb + mO.z + lane * 2);
        short c3 = *(const short*)(xbb + mO.w + lane * 2);
        float s = mW.x * bf2f(c0) + mW.y * bf2f(c1)
                + mW.z * bf2f(c2) + mW.w * bf2f(c3);
        S[(size_t)t * 64 + lane] = f2bf(s);
    }
}

// ---------------------------------------------------------------------------
// k_gemm: out[px][o] = sum_{f,c} S[f][px][c] * w[o][c][f]  + bias.
// Block 256 thr / 4 waves = 32 px x 64 o; wave = n-strip of 16 o, full K.
// A-tiles: double-buffered XOR-swizzled LDS (coalesced staging); B-frags
// (weights) preloaded to 72 VGPR once. Epilogue via LDS transpose.
// Grid 1024 (= (b*64+i)*2+half), 4 blocks/CU.
// ---------------------------------------------------------------------------
__global__ __launch_bounds__(256, 4) void k_gemm(
        const short* __restrict__ S, const short* __restrict__ wt2,
        const float* __restrict__ bias, float* __restrict__ out) {
    __shared__ __align__(16) char smem[8448];        // dbuf 2x4096; s_fin aliases
    float* s_fin = (float*)smem;                     // [64 o][33] f32

    int tid  = threadIdx.x;
    int lane = tid & 63;
    int wv   = __builtin_amdgcn_readfirstlane((int)(tid >> 6));
    int blk  = blockIdx.x;                           // (b*64+i)*2 + half
    int b = blk >> 7, i = (blk >> 1) & 63, jb = (blk & 1) * 32;
    int P0 = blk * 32;

    int arow = lane & 15, cg = lane >> 4, cgb = cg * 8;

    // ---- B-frags: wave's 16-o strip, all 9 taps x 2 k-chunks (72 VGPR)
    bf16x8 bfrag[9][2];
    {
        int o = wv * 16 + arow;
        #pragma unroll
        for (int f = 0; f < 9; ++f)
            #pragma unroll
            for (int kk = 0; kk < 2; ++kk)
                bfrag[f][kk] = *(const bf16x8*)(wt2 + (f * 64 + o) * 64 + kk * 32 + cgb);
    }

    // ---- staging thread mapping: 32 px x 8 chunks of 16 B
    int spx = tid >> 3, schunk = tid & 7;
    int sdst = spx * 128 + ((schunk << 4) ^ ((spx & 7) << 4));
    #define SSRC(F) (S + ((size_t)(((F) << 15) + P0 + spx)) * 64 + schunk * 8)

    // prologue: stage f=0 into buf0
    *(short8v*)(smem + sdst) = *(const short8v*)SSRC(0);
    __syncthreads();

    f32x4 acc[2];
    acc[0] = (f32x4){0.f,0.f,0.f,0.f};
    acc[1] = (f32x4){0.f,0.f,0.f,0.f};

    for (int f = 0; f < 9; ++f) {
        int curb = (f & 1) * 4096;
        short8v ldv;
        if (f < 8) ldv = *(const short8v*)SSRC(f + 1);   // in flight over MFMA
        #pragma unroll
        for (int kk = 0; kk < 2; ++kk)
            #pragma unroll
            for (int mf = 0; mf < 2; ++mf) {
                int px = mf * 16 + arow;
                const char* ap = smem + curb + px * 128
                               + ((kk * 64 + cg * 16) ^ ((px & 7) << 4));
                acc[mf] = __builtin_amdgcn_mfma_f32_16x16x32_bf16(
                    *(const bf16x8*)ap, bfrag[f][kk], acc[mf], 0, 0, 0);
            }
        if (f < 8) *(short8v*)(smem + (curb ^ 4096) + sdst) = ldv;
        __syncthreads();
    }
    #undef SSRC

    // ---- epilogue: acc (col=o, row=px) -> s_fin[o][px] -> coalesced store
    {
        int o = wv * 16 + arow;
        #pragma unroll
        for (int mf = 0; mf < 2; ++mf)
            #pragma unroll
            for (int r = 0; r < 4; ++r)
                s_fin[o * 33 + mf * 16 + cg * 4 + r] = acc[mf][r];
    }
    __syncthreads();
    {
        int o = tid >> 2, q = tid & 3;
        float bv = bias[o];
        float* op = out + ((size_t)(b * 64 + o)) * 4096 + i * 64 + jb + q * 8;
        float4 v0, v1;
        v0.x = s_fin[o * 33 + q * 8 + 0] + bv;
        v0.y = s_fin[o * 33 + q * 8 + 1] + bv;
        v0.z = s_fin[o * 33 + q * 8 + 2] + bv;
        v0.w = s_fin[o * 33 + q * 8 + 3] + bv;
        v1.x = s_fin[o * 33 + q * 8 + 4] + bv;
        v1.y = s_fin[o * 33 + q * 8 + 5] + bv;
        v1.z = s_fin[o * 33 + q * 8 + 6] + bv;
        v1.w = s_fin[o * 33 + q * 8 + 7] + bv;
        *(float4*)op       = v0;
        *(float4*)(op + 4) = v1;
    }
}

// ---------------------------------------------------------------------------
extern "C" void kernel_launch(void* const* d_in, const int* in_sizes, int n_in,
                              void* d_out, int out_size, void* d_ws, size_t ws_size,
                              hipStream_t stream) {
    const float* x     = (const float*)d_in[0];
    const float* w_off = (const float*)d_in[1];
    const float* b_off = (const float*)d_in[2];
    const float* w_mod = (const float*)d_in[3];
    const float* b_mod = (const float*)d_in[4];
    const float* w     = (const float*)d_in[5];
    const float* bias  = (const float*)d_in[6];
    float* out = (float*)d_out;

    char* ws = (char*)d_ws;
    short*  xt    = (short*)(ws);                    //  4,194,304 B
    short*  wt2   = (short*)(ws + 4194304);          //     73,728 B
    short*  wc2   = (short*)(ws + 4268032);          //     36,864 B
    float4* metaW = (float4*)(ws + 4304896);         //  4,718,592 B
    int4*   metaO = (int4*)(ws + 9023488);           //  4,718,592 B
    short*  S     = (short*)(ws + 13742080);         // 37,748,736 B

    hipLaunchKernelGGL(k_prep,      dim3(216),  dim3(256), 0, stream, w, w_off, w_mod, wt2, wc2);
    hipLaunchKernelGGL(k_transpose, dim3(512),  dim3(256), 0, stream, x, xt);
    hipLaunchKernelGGL(k_convmeta,  dim3(512),  dim3(256), 0, stream,
                       xt, wc2, b_off, b_mod, metaW, metaO);
    hipLaunchKernelGGL(k_sample,    dim3(2048), dim3(256), 0, stream,
                       xt, metaW, metaO, S);
    hipLaunchKernelGGL(k_gemm,      dim3(1024), dim3(256), 0, stream,
                       S, wt2, bias, out);
}